// Round 5
// baseline (70.759 us; speedup 1.0000x reference)
//
#include <hip/hip_runtime.h>
#include <hip/hip_bf16.h>

// loss = mean_b (out_b - label_b)^2
// out_b = sqrt(s_ab) / (s_aa^(1/4) * s_bb^(1/4)),  s_xy = ||X Y^T||_F^2.
// S-side products (rows of A/B; K = D = 384; no transpose staging).
// 2560 uniform jobs of one 64x128 tile each:
//   per batch (20): AB full (8, w1); AA upper-tri (6, w {1,1,2,2,1,1});
//   BB same. 512 persistent WGs x 5 jobs = one continuous 30-chunk
//   pipeline per WG (BK=64, dbuf LDS, loads issued early - T14).
// LDS layout = R1's measured-zero-conflict recipe: [row][64 cols] bf16,
// 8B subchunks, subchunk u stored at u ^ (row & 15); frag = 2x b64.

typedef short short8  __attribute__((ext_vector_type(8)));
typedef short short4_ __attribute__((ext_vector_type(4)));
typedef float f32x16  __attribute__((ext_vector_type(16)));

constexpr int S  = 256;
constexpr int D  = 384;
constexpr int BK = 64;

__device__ __forceinline__ short bf16_of(float f){
    __hip_bfloat16 h = __float2bfloat16(f);   // RNE
    short s; __builtin_memcpy(&s, &h, 2); return s;
}

__global__ __launch_bounds__(512, 4)
void gram(const float* __restrict__ A, const float* __restrict__ B,
          float* __restrict__ ws)
{
    __shared__ short lds[2][192 * 64];   // 2 x 24 KiB

    const int w    = blockIdx.x;
    const int xcd  = w & 7;              // batch pinned to one XCD
    const int i    = w >> 3;             // 0..63
    const int batch= (xcd << 4) + (i >> 2);
    const int t0   = 5 * (i & 3);        // first of 5 jobs in [0,20)

    const float* const Abase = A + (size_t)batch * S * D;
    const float* const Bbase = B + (size_t)batch * S * D;

    const int tid  = threadIdx.x;
    const int lane = tid & 63;
    const int wv   = tid >> 6;           // 0..7
    const int l31  = lane & 31;

    // ---- staging map: thread -> (row0 = tid>>4, subchunk u = tid&15) ----
    const int row0  = tid >> 4;          // 0..31; rows row0+32q, q=0..5
    const int u     = tid & 15;
    const int su    = u ^ (row0 & 15);   // invariant across q (32q % 16 == 0)
    const int wb_hw = row0 * 64 + (su << 2);       // halfword offset
    const int goff0 = row0 * D + u * 4;            // + kc*64 (+ 32q*D)

    // ---- frag-read offsets (halfwords), chunk-invariant ----
    const int sx = ((wv >> 2) * 32) + l31;         // X stack row 0..63
    const int sy = 64 + ((wv & 3) * 32) + l31;     // Y stack row 64..191
    const int kh = lane >> 5;
    int roX[4], roY[4];
    #pragma unroll
    for (int ks = 0; ks < 4; ++ks) {
        const int u0 = ks * 4 + 2 * kh;            // even
        roX[ks] = sx * 64 + ((u0 ^ (l31 & 15)) << 2);
        roY[ks] = sy * 64 + ((u0 ^ (l31 & 15)) << 2);
    }

    // ---- job table (uniform scalar) ----
    auto job_params = [&](int t, const float*& pX, const float*& pY,
                          int& ty, float& wt) {
        if (t < 8) {                                  // AB
            pX = Abase + (size_t)(t >> 1) * 64 * D;
            pY = Bbase + (size_t)(t & 1) * 128 * D;
            ty = 0; wt = 1.f;
        } else {                                      // AA / BB upper-tri
            int uu = t - 8;
            const float* base = Abase; ty = 1;
            if (uu >= 6) { uu -= 6; base = Bbase; ty = 2; }
            const int xb = (uu < 4) ? (uu & 1) : (uu - 2);
            const int yb = (uu >= 2);
            pX = base + (size_t)xb * 64 * D;
            pY = base + (size_t)yb * 128 * D;
            wt = (uu == 2 || uu == 3) ? 2.f : 1.f;
        }
    };

    f32x16 acc;
    #pragma unroll
    for (int e = 0; e < 16; ++e) acc[e] = 0.f;
    float sab = 0.f, saa = 0.f, sbb = 0.f;
    float4 v[6];

#define LOADS(pX, pY, kc) { \
    const int off = goff0 + (kc) * BK; \
    v[0] = *(const float4*)((pX) + off); \
    v[1] = *(const float4*)((pX) + off + 32 * D); \
    _Pragma("unroll") for (int q = 0; q < 4; ++q) \
        v[2 + q] = *(const float4*)((pY) + off + q * 32 * D); }

#define WRITES(bs) { \
    short* Lb = lds[bs]; \
    _Pragma("unroll") for (int q = 0; q < 6; ++q) { \
        short4_ pk; \
        pk[0] = bf16_of(v[q].x); pk[1] = bf16_of(v[q].y); \
        pk[2] = bf16_of(v[q].z); pk[3] = bf16_of(v[q].w); \
        *(short4_*)&Lb[wb_hw + q * 2048] = pk; } }

#define COMPUTE(bs) { \
    const short* Lb = lds[bs]; \
    _Pragma("unroll") for (int ks = 0; ks < 4; ++ks) { \
        short8 xf, yf; \
        *(short4_*)&xf     = *(const short4_*)&Lb[roX[ks]]; \
        ((short4_*)&xf)[1] = *(const short4_*)&Lb[roX[ks] ^ 4]; \
        *(short4_*)&yf     = *(const short4_*)&Lb[roY[ks]]; \
        ((short4_*)&yf)[1] = *(const short4_*)&Lb[roY[ks] ^ 4]; \
        acc = __builtin_amdgcn_mfma_f32_32x32x16_bf16(xf, yf, acc, 0, 0, 0); } }

    // ---- persistent 30-chunk stream over 5 jobs ----
    const float *pX, *pY, *pXn, *pYn;
    int ty, tyn; float wt, wtn;
    job_params(t0, pX, pY, ty, wt);
    LOADS(pX, pY, 0);
    WRITES(0);
    __syncthreads();

    for (int jj = 0; jj < 5; ++jj) {
        job_params(t0 + ((jj < 4) ? jj + 1 : jj), pXn, pYn, tyn, wtn);
        #pragma unroll
        for (int kc = 0; kc < 6; ++kc) {
            if (kc < 5) { LOADS(pX, pY, kc + 1); }   // issue early (T14)
            else        { LOADS(pXn, pYn, 0); }      // next job's chunk 0
            COMPUTE(kc & 1);
            if (kc == 5) {                            // job end: square-dump
                float s = 0.f;
                #pragma unroll
                for (int e = 0; e < 16; ++e) s += acc[e] * acc[e];
                s *= wt;
                if (ty == 0) sab += s; else if (ty == 1) saa += s; else sbb += s;
                #pragma unroll
                for (int e = 0; e < 16; ++e) acc[e] = 0.f;
            }
            WRITES((kc + 1) & 1);
            __syncthreads();
        }
        pX = pXn; pY = pYn; ty = tyn; wt = wtn;
    }

    // ---- WG reduce 3 scalars -> ws[w*3 + {ab,aa,bb}] ----
    #pragma unroll
    for (int o = 32; o > 0; o >>= 1) {
        sab += __shfl_xor(sab, o, 64);
        saa += __shfl_xor(saa, o, 64);
        sbb += __shfl_xor(sbb, o, 64);
    }
    float* red = (float*)lds;          // safe: all compute done (last barrier)
    if (lane == 0) { red[wv] = sab; red[8 + wv] = saa; red[16 + wv] = sbb; }
    __syncthreads();
    if (tid == 0) {
        float r0 = 0.f, r1 = 0.f, r2 = 0.f;
        #pragma unroll
        for (int k = 0; k < 8; ++k) {
            r0 += red[k]; r1 += red[8 + k]; r2 += red[16 + k];
        }
        ws[w * 3 + 0] = r0; ws[w * 3 + 1] = r1; ws[w * 3 + 2] = r2;
    }
}

__global__ void finalize(const float* __restrict__ ws,
                         const float* __restrict__ labels,
                         float* __restrict__ out)
{
    __shared__ float red[128];
    const int b = threadIdx.x;                 // one thread per batch
    const int x = b >> 4, m = b & 15;
    float sab = 0.f, saa = 0.f, sbb = 0.f;
    #pragma unroll
    for (int q = 0; q < 4; ++q) {
        const int w = (((m << 2) + q) << 3) | x;   // the batch's 4 WGs
        sab += ws[w * 3 + 0]; saa += ws[w * 3 + 1]; sbb += ws[w * 3 + 2];
    }
    const float outb = sqrtf(sab) / (sqrtf(sqrtf(saa)) * sqrtf(sqrtf(sbb)));
    const float d    = outb - labels[b];
    red[b] = d * d * (1.0f / 128.0f);
    __syncthreads();
    for (int off = 64; off > 0; off >>= 1) {
        if (b < off) red[b] += red[b + off];
        __syncthreads();
    }
    if (b == 0) out[0] = red[0];
}

extern "C" void kernel_launch(void* const* d_in, const int* in_sizes, int n_in,
                              void* d_out, int out_size, void* d_ws, size_t ws_size,
                              hipStream_t stream)
{
    const float* A      = (const float*)d_in[0];
    const float* B      = (const float*)d_in[1];
    const float* labels = (const float*)d_in[2];
    float* ws = (float*)d_ws;   // 512*3 floats, all written every launch

    gram<<<dim3(512), dim3(512), 0, stream>>>(A, B, ws);
    finalize<<<dim3(1), dim3(128), 0, stream>>>(ws, labels, (float*)d_out);
}

// Round 6
// 50.708 us; speedup vs baseline: 1.3954x; 1.3954x over previous
//
#include <hip/hip_runtime.h>
#include <hip/hip_bf16.h>

// loss = mean_b (out_b - label_b)^2
// out_b = sqrt(s_ab) / (s_aa^(1/4) * s_bb^(1/4)),  s_xy = ||X Y^T||_F^2.
//
// R1 skeleton (best measured: dbuf + issue-early loads, non-persistent,
// XCD-pinned batches, verified-zero-conflict LDS recipe) with:
//   - BK=32 -> 48 KB dbuf -> 3 blocks/CU; 6 WGs/batch = 768 WGs = 3/CU.
//   - 48 uniform 64x64 tile-jobs per batch, 1 per wave, no weights:
//       t0: AA rows{0,1}x cols 0..3   t2/t3: BB same       (full 4x4 grids;
//       t1: AA rows{2,3}x cols 0..3   t4: A{0,1}xB, t5: A{2,3}xB  sym dropped)
//   - LDS: paired-row lines (line=row>>1, 16 8B-slots, slot = s ^ (line&15))
//     == R1's measured-zero-conflict XOR-16 pattern at BK=32.

typedef short short8  __attribute__((ext_vector_type(8)));
typedef short short4_ __attribute__((ext_vector_type(4)));
typedef float f32x16  __attribute__((ext_vector_type(16)));

constexpr int S = 256, D = 384, BK = 32, NCH = 12;

__device__ __forceinline__ short bf16_of(float f){
    __hip_bfloat16 h = __float2bfloat16(f);   // RNE
    short s; __builtin_memcpy(&s, &h, 2); return s;
}

#define MFMA(a,b,c) __builtin_amdgcn_mfma_f32_32x32x16_bf16(a, b, c, 0, 0, 0)

__global__ __launch_bounds__(512, 4)
void gram(const float* __restrict__ A, const float* __restrict__ B,
          float* __restrict__ ws)
{
    __shared__ short lds[2][384 * BK];   // 2 x 24 KiB

    // bid&7 = XCD; all 6 WGs of a batch share one XCD (L2 reuse).
    const int bid = blockIdx.x;
    const int xcd = bid & 7;
    const int idx = bid >> 3;            // 0..95
    const int bl  = idx / 6;
    const int ty  = idx - bl * 6;
    const int batch = (xcd << 4) + bl;

    const float* Ab = A + (size_t)batch * S * D;
    const float* Bb = B + (size_t)batch * S * D;

    const int tid  = threadIdx.x;
    const int lane = tid & 63;
    const int wv   = tid >> 6;           // 0..7
    const int l31  = lane & 31;
    const int kh   = lane >> 5;

    // stack: t0/t1 = A (256 rows); t2/t3 = B; t4 = A-lo + B (384); t5 = A-hi + B
    const int nit = (ty < 4) ? 4 : 6;    // 64-row groups per chunk

    // ---- staging map: r0 = tid>>3 (0..63), u = tid&7; rows r0 + 64*i ----
    const int r0 = tid >> 3;
    const int u  = tid & 7;
    const float* gsrc[6];
    #pragma unroll
    for (int i = 0; i < 6; ++i) {
        const int r = i * 64 + r0;       // stack row
        const float* p;
        if (ty < 2)       p = Ab + (size_t)r * D;
        else if (ty < 4)  p = Bb + (size_t)r * D;
        else if (r < 128) p = Ab + (size_t)((ty == 5) ? r + 128 : r) * D;
        else              p = Bb + (size_t)(r - 128) * D;
        gsrc[i] = p + u * 4;
    }
    // LDS write offset (halfwords); +i*2048 per 64-row group.
    // line = r>>1 (64 hw per line), slot s = u + 8*(r&1), swz = s ^ (line&15).
    const int wb = (r0 >> 1) * 64 +
                   (((u + ((r0 & 1) << 3)) ^ ((r0 >> 1) & 15)) << 2);

    // ---- per-wave job: X rows [xb,xb+64), Y rows [yb,yb+64) of the stack ----
    int xb, yb;
    if (ty < 4) { xb = (((ty & 1) << 1) + (wv >> 2)) * 64; yb = (wv & 3) * 64; }
    else        { xb = (wv >> 2) * 64;                     yb = 128 + (wv & 3) * 64; }

    // frag read offsets (hw), ks=0,1; row = base + l31 (+32 => +1024 hw);
    // frag k-span = subchunks s,s+1 with s = ks*4 + kh*2 + 8*(row&1).
    int roX[2], roY[2];
    #pragma unroll
    for (int ks = 0; ks < 2; ++ks) {
        const int s   = ks * 4 + kh * 2 + ((l31 & 1) << 3);
        const int x16 = l31 >> 1;
        const int sw  = ((s ^ x16) << 2) + x16 * 64;
        roX[ks] = xb * 32 + sw;
        roY[ks] = yb * 32 + sw;
    }

    f32x16 a00 = {}, a01 = {}, a10 = {}, a11 = {};
    float4 v[6];

#define LOADS(kc) { _Pragma("unroll") for (int i = 0; i < 6; ++i) \
    if (i < nit) v[i] = *(const float4*)(gsrc[i] + (kc) * BK); }

#define WRITES(bs) { short* Lb = lds[bs]; \
    _Pragma("unroll") for (int i = 0; i < 6; ++i) if (i < nit) { \
        short4_ pk; \
        pk[0] = bf16_of(v[i].x); pk[1] = bf16_of(v[i].y); \
        pk[2] = bf16_of(v[i].z); pk[3] = bf16_of(v[i].w); \
        *(short4_*)&Lb[wb + i * 2048] = pk; } }

#define FRAG(dst, off) { \
    *(short4_*)&dst     = *(const short4_*)&Lb[(off)]; \
    ((short4_*)&dst)[1] = *(const short4_*)&Lb[(off) ^ 4]; }

#define COMPUTE(bs) { const short* Lb = lds[bs]; \
    _Pragma("unroll") for (int ks = 0; ks < 2; ++ks) { \
        short8 x0, x1, y0, y1; \
        FRAG(x0, roX[ks]);        FRAG(x1, roX[ks] + 1024); \
        FRAG(y0, roY[ks]);        FRAG(y1, roY[ks] + 1024); \
        a00 = MFMA(x0, y0, a00);  a01 = MFMA(x0, y1, a01); \
        a10 = MFMA(x1, y0, a10);  a11 = MFMA(x1, y1, a11); } }

    // ---- main loop: issue next chunk's loads early (T14), dbuf LDS ----
    LOADS(0); WRITES(0); __syncthreads();
    for (int c = 0; c < NCH; ++c) {
        if (c + 1 < NCH) LOADS(c + 1);
        COMPUTE(c & 1);
        if (c + 1 < NCH) WRITES((c + 1) & 1);
        __syncthreads();
    }

    // ---- square-accumulate -> one scalar per WG ----
    float sum = 0.f;
    #pragma unroll
    for (int e = 0; e < 16; ++e)
        sum += a00[e]*a00[e] + a01[e]*a01[e] + a10[e]*a10[e] + a11[e]*a11[e];
    #pragma unroll
    for (int o = 32; o > 0; o >>= 1) sum += __shfl_xor(sum, o, 64);
    float* red = (float*)lds;      // safe: barrier after last COMPUTE
    if (lane == 0) red[wv] = sum;
    __syncthreads();
    if (tid == 0) {
        float t = 0.f;
        #pragma unroll
        for (int k = 0; k < 8; ++k) t += red[k];
        ws[bid] = t;
    }
}

__global__ void finalize(const float* __restrict__ ws,
                         const float* __restrict__ labels,
                         float* __restrict__ out)
{
    __shared__ float red[128];
    const int b = threadIdx.x;             // one thread per batch
    const int xc = b >> 4, bl = b & 15;
    #define W(t) ws[(((bl * 6 + (t)) << 3) | xc)]
    const float saa = W(0) + W(1);
    const float sbb = W(2) + W(3);
    const float sab = W(4) + W(5);
    #undef W
    const float outb = sqrtf(sab) / (sqrtf(sqrtf(saa)) * sqrtf(sqrtf(sbb)));
    const float d    = outb - labels[b];
    red[b] = d * d * (1.0f / 128.0f);
    __syncthreads();
    for (int off = 64; off > 0; off >>= 1) {
        if (b < off) red[b] += red[b + off];
        __syncthreads();
    }
    if (b == 0) out[0] = red[0];
}

extern "C" void kernel_launch(void* const* d_in, const int* in_sizes, int n_in,
                              void* d_out, int out_size, void* d_ws, size_t ws_size,
                              hipStream_t stream)
{
    const float* A      = (const float*)d_in[0];
    const float* B      = (const float*)d_in[1];
    const float* labels = (const float*)d_in[2];
    float* ws = (float*)d_ws;   // 768 floats, all written every launch

    gram<<<dim3(768), dim3(512), 0, stream>>>(A, B, ws);
    finalize<<<dim3(1), dim3(128), 0, stream>>>(ws, labels, (float*)d_out);
}